// Round 5
// baseline (1191.238 us; speedup 1.0000x reference)
//
#include <hip/hip_runtime.h>

// Problem constants
#define NPIX 8192      // B*H*W
#define EDIM 256
#define KCB  8192
#define OUT_ZQ   0
#define OUT_DIFF 2097152
#define OUT_IND  2097153

// ws layout (bytes) — total 331,776 <= proven 565,248
#define WS_A     0         // 8192 f32  np-pairwise ||z_e||^2
#define WS_N     32768     // 8192 f32  np-pairwise ||e||^2
#define WS_PAIRS 65536     // 8192*4 float2 = 256 KB
#define WS_PART  327680    // 1024 f32

// ---------------------------------------------------------------- z_e: bit-exact np.einsum replica
// acc_c = fl(acc + fl(z_c * w_ec)) ascending c (scalar mul+add, no fma), then fl(acc + pb_e).
// grid 512 = 8 b x 64 hw-tiles(16 px); 256 thr = e.
__global__ __launch_bounds__(256) void k_ze_np(const float* __restrict__ z,
                                               const float* __restrict__ pw,
                                               const float* __restrict__ pb,
                                               float* __restrict__ ze) {
    __shared__ float lz[32][16];
    __shared__ float lw[256][33];
    const int t   = threadIdx.x;
    const int b   = blockIdx.x >> 6;
    const int hw0 = (blockIdx.x & 63) * 16;

    float acc[16];
#pragma unroll
    for (int p = 0; p < 16; ++p) acc[p] = 0.0f;

    for (int cc = 0; cc < 256; cc += 32) {
        float4 wv[8];
        const float4* wsrc = reinterpret_cast<const float4*>(pw + (size_t)t * 256 + cc);
#pragma unroll
        for (int i = 0; i < 8; ++i) wv[i] = wsrc[i];
        float zv[2];
#pragma unroll
        for (int i = 0; i < 2; ++i) {
            const int f = t + i * 256;           // 0..511
            zv[i] = z[(size_t)(b * 256 + cc + (f >> 4)) * 1024 + hw0 + (f & 15)];
        }
        __syncthreads();   // previous chunk's reads complete
#pragma unroll
        for (int i = 0; i < 8; ++i) {
            lw[t][i * 4 + 0] = wv[i].x;
            lw[t][i * 4 + 1] = wv[i].y;
            lw[t][i * 4 + 2] = wv[i].z;
            lw[t][i * 4 + 3] = wv[i].w;
        }
#pragma unroll
        for (int i = 0; i < 2; ++i) {
            const int f = t + i * 256;
            lz[f >> 4][f & 15] = zv[i];
        }
        __syncthreads();
#pragma unroll 8
        for (int cl = 0; cl < 32; ++cl) {
            const float wl = lw[t][cl];
#pragma unroll
            for (int p = 0; p < 16; ++p)
                acc[p] = __fadd_rn(acc[p], __fmul_rn(lz[cl][p], wl));
        }
    }
    const float bb = pb[t];
#pragma unroll
    for (int p = 0; p < 16; ++p)
        ze[(size_t)(b * 1024 + hw0 + p) * 256 + t] = __fadd_rn(acc[p], bb);
}

// ---------------------------------------------------------------- np.sum(x*x, axis=1) pairwise replica (n=256)
// block0..31 -> A rows (z_e), block 32..63 -> N rows (embed)
__global__ __launch_bounds__(256) void k_rowstats(const float* __restrict__ ze,
                                                  const float* __restrict__ embed,
                                                  float* __restrict__ A,
                                                  float* __restrict__ Nf) {
    const int gid = blockIdx.x * 256 + threadIdx.x;     // 0..16383
    const float* row = (gid < 8192) ? (ze + (size_t)gid * 256)
                                    : (embed + (size_t)(gid - 8192) * 256);
    float blk[2];
#pragma unroll
    for (int half = 0; half < 2; ++half) {
        const float4* r4 = reinterpret_cast<const float4*>(row + half * 128);
        float r[8];
#pragma unroll
        for (int i = 0; i < 16; ++i) {
            const float4 a = r4[i * 2], b = r4[i * 2 + 1];
            const float s[8] = {__fmul_rn(a.x, a.x), __fmul_rn(a.y, a.y),
                                __fmul_rn(a.z, a.z), __fmul_rn(a.w, a.w),
                                __fmul_rn(b.x, b.x), __fmul_rn(b.y, b.y),
                                __fmul_rn(b.z, b.z), __fmul_rn(b.w, b.w)};
            if (i == 0) {
#pragma unroll
                for (int j = 0; j < 8; ++j) r[j] = s[j];
            } else {
#pragma unroll
                for (int j = 0; j < 8; ++j) r[j] = __fadd_rn(r[j], s[j]);
            }
        }
        blk[half] = __fadd_rn(__fadd_rn(__fadd_rn(r[0], r[1]), __fadd_rn(r[2], r[3])),
                              __fadd_rn(__fadd_rn(r[4], r[5]), __fadd_rn(r[6], r[7])));
    }
    const float res = __fadd_rn(blk[0], blk[1]);
    if (gid < 8192) A[gid] = res;
    else            Nf[gid - 8192] = res;
}

// ---------------------------------------------------------------- dist replica + argmin (first occurrence)
// M2 = fmaf-chain over c ascending of (2*z_e)*e  (== OpenBLAS sgemm chain of (2.0*flat)@embed.T)
// v = fl(fl(A - M2) + N); lexicographic (v, k) argmin.
// grid 512 = 128 px-tiles(64 px) x 4 k-splits(2048 k); thread tile 8 px x 8 k.
__global__ __launch_bounds__(256) void k_dist_np(const float* __restrict__ ze,
                                                 const float* __restrict__ embed,
                                                 const float* __restrict__ A,
                                                 const float* __restrict__ Nf,
                                                 float2* __restrict__ pairs) {
    __shared__ float le[32][256];
    __shared__ float red[64][32][2];
    const int t    = threadIdx.x;
    const int ks   = blockIdx.x & 3;
    const int pt   = blockIdx.x >> 2;
    const int pix0 = pt * 64;
    const int k0   = ks * 2048;
    const int tp   = t & 7, tk = t >> 3;

    float best[8];
    int   bidx[8];
#pragma unroll
    for (int i = 0; i < 8; ++i) { best[i] = 3.402823466e+38f; bidx[i] = 0x7fffffff; }

    const float* zbase = ze + (size_t)(pix0 + tp * 8) * 256;
    float Ai[8];
#pragma unroll
    for (int i = 0; i < 8; ++i) Ai[i] = A[pix0 + tp * 8 + i];

    for (int kc = 0; kc < 2048; kc += 256) {
        float acc[8][8];
#pragma unroll
        for (int i = 0; i < 8; ++i)
#pragma unroll
            for (int j = 0; j < 8; ++j) acc[i][j] = 0.0f;

        const float* erow = embed + (size_t)(k0 + kc + t) * 256;

        for (int cc = 0; cc < 256; cc += 32) {
            float4 st[8];
            const float4* src = reinterpret_cast<const float4*>(erow + cc);
#pragma unroll
            for (int m = 0; m < 8; ++m) st[m] = src[m];
            __syncthreads();
#pragma unroll
            for (int m = 0; m < 8; ++m) {
                le[m * 4 + 0][t] = st[m].x;
                le[m * 4 + 1][t] = st[m].y;
                le[m * 4 + 2][t] = st[m].z;
                le[m * 4 + 3][t] = st[m].w;
            }
            __syncthreads();
#pragma unroll 4
            for (int c2 = 0; c2 < 32; c2 += 2) {
                float2 zf[8];
#pragma unroll
                for (int i = 0; i < 8; ++i)
                    zf[i] = *reinterpret_cast<const float2*>(zbase + (size_t)i * 256 + cc + c2);
                float4 ea0 = *reinterpret_cast<const float4*>(&le[c2][tk * 8]);
                float4 ea1 = *reinterpret_cast<const float4*>(&le[c2][tk * 8 + 4]);
                float4 eb0 = *reinterpret_cast<const float4*>(&le[c2 + 1][tk * 8]);
                float4 eb1 = *reinterpret_cast<const float4*>(&le[c2 + 1][tk * 8 + 4]);
                float ea[8] = {ea0.x, ea0.y, ea0.z, ea0.w, ea1.x, ea1.y, ea1.z, ea1.w};
                float eb[8] = {eb0.x, eb0.y, eb0.z, eb0.w, eb1.x, eb1.y, eb1.z, eb1.w};
#pragma unroll
                for (int i = 0; i < 8; ++i) {
                    const float zx2 = __fmul_rn(2.0f, zf[i].x);   // exact, matches (2.0*flat)
                    const float zy2 = __fmul_rn(2.0f, zf[i].y);
#pragma unroll
                    for (int j = 0; j < 8; ++j)
                        acc[i][j] = fmaf(zy2, eb[j], fmaf(zx2, ea[j], acc[i][j]));
                }
            }
        }
        // dist values for this chunk; k ascending within thread -> strict < keeps first occurrence
#pragma unroll
        for (int j = 0; j < 8; ++j) {
            const int   k  = k0 + kc + tk * 8 + j;
            const float nk = Nf[k];
#pragma unroll
            for (int i = 0; i < 8; ++i) {
                const float v = __fadd_rn(__fsub_rn(Ai[i], acc[i][j]), nk);
                if (v < best[i]) { best[i] = v; bidx[i] = k; }
            }
        }
    }
    __syncthreads();
#pragma unroll
    for (int i = 0; i < 8; ++i) {
        red[tp * 8 + i][tk][0] = best[i];
        red[tp * 8 + i][tk][1] = __int_as_float(bidx[i]);
    }
    __syncthreads();
    if (t < 64) {
        float bv = 3.402823466e+38f;
        int   bk = 0x7fffffff;
#pragma unroll 4
        for (int q = 0; q < 32; ++q) {
            const float v  = red[t][q][0];
            const int   ki = __float_as_int(red[t][q][1]);
            if (v < bv || (v == bv && ki < bk)) { bv = v; bk = ki; }
        }
        pairs[(size_t)(pix0 + t) * 4 + ks] = make_float2(bv, (float)bk);
    }
}

// ---------------------------------------------------------------- combine 4 k-splits (lexicographic)
__global__ __launch_bounds__(256) void k_combine(const float2* __restrict__ pairs,
                                                 float* __restrict__ out_ind) {
    const int n = blockIdx.x * 256 + threadIdx.x;
    float bv = 3.402823466e+38f;
    float bk = 1.0e9f;
#pragma unroll
    for (int s = 0; s < 4; ++s) {
        const float2 p = pairs[(size_t)n * 4 + s];
        if (p.x < bv || (p.x == bv && p.y < bk)) { bv = p.x; bk = p.y; }
    }
    out_ind[n] = bk;
}

// ---------------------------------------------------------------- gather z_q (overwrite z_e) + partial MSE (f64)
__global__ __launch_bounds__(256) void k_gather(const float* __restrict__ embed,
                                                float* __restrict__ out,
                                                const float* __restrict__ out_ind,
                                                float* __restrict__ part) {
    __shared__ double wsum[4];
    const int t = threadIdx.x;
    const int g = t >> 5, l = t & 31;
    const int n = blockIdx.x * 8 + g;
    const int idx = (int)(out_ind[n] + 0.5f);
    const float4* ev4 = reinterpret_cast<const float4*>(embed + (size_t)idx * EDIM);
    float4* zp = reinterpret_cast<float4*>(out + (size_t)n * EDIM);
    double s = 0.0;
#pragma unroll
    for (int r = 0; r < 2; ++r) {
        const float4 ev = ev4[l + r * 32];
        const float4 zv = zp[l + r * 32];
        const double dx = (double)ev.x - zv.x, dy = (double)ev.y - zv.y;
        const double dz = (double)ev.z - zv.z, dw = (double)ev.w - zv.w;
        s += dx * dx + dy * dy + dz * dz + dw * dw;
        zp[l + r * 32] = ev;             // z_q_st == z_q numerically
    }
    for (int off = 32; off; off >>= 1) s += __shfl_down(s, off, 64);
    const int wid = t >> 6, lane = t & 63;
    if (lane == 0) wsum[wid] = s;
    __syncthreads();
    if (t == 0) part[blockIdx.x] = (float)(wsum[0] + wsum[1] + wsum[2] + wsum[3]);
}

// ---------------------------------------------------------------- final diff reduction (f64)
__global__ __launch_bounds__(256) void k_final(const float* __restrict__ part,
                                               float* __restrict__ out_diff) {
    __shared__ double wsum[4];
    double s = 0.0;
#pragma unroll
    for (int i = 0; i < 4; ++i) s += (double)part[threadIdx.x + i * 256];
    for (int off = 32; off; off >>= 1) s += __shfl_down(s, off, 64);
    const int wid = threadIdx.x >> 6, lane = threadIdx.x & 63;
    if (lane == 0) wsum[wid] = s;
    __syncthreads();
    if (threadIdx.x == 0)
        out_diff[0] = (float)(2.0 * (wsum[0] + wsum[1] + wsum[2] + wsum[3]) / 2097152.0);
}

extern "C" void kernel_launch(void* const* d_in, const int* in_sizes, int n_in,
                              void* d_out, int out_size, void* d_ws, size_t ws_size,
                              hipStream_t stream) {
    const float* z     = (const float*)d_in[0];
    const float* pw    = (const float*)d_in[1];
    const float* pb    = (const float*)d_in[2];
    const float* embed = (const float*)d_in[3];
    float* out = (float*)d_out;
    char*  ws  = (char*)d_ws;

    float*  A     = (float*)(ws + WS_A);
    float*  Nf    = (float*)(ws + WS_N);
    float2* pairs = (float2*)(ws + WS_PAIRS);
    float*  part  = (float*)(ws + WS_PART);

    float* ze       = out + OUT_ZQ;      // z_e lives in z_q slot, overwritten by gather
    float* out_diff = out + OUT_DIFF;
    float* out_ind  = out + OUT_IND;

    k_ze_np   <<<512,  256, 0, stream>>>(z, pw, pb, ze);
    k_rowstats<<<64,   256, 0, stream>>>(ze, embed, A, Nf);
    k_dist_np <<<512,  256, 0, stream>>>(ze, embed, A, Nf, pairs);
    k_combine <<<32,   256, 0, stream>>>(pairs, out_ind);
    k_gather  <<<1024, 256, 0, stream>>>(embed, out + OUT_ZQ, out_ind, part);
    k_final   <<<1,    256, 0, stream>>>(part, out_diff);
}

// Round 6
// 562.816 us; speedup vs baseline: 2.1166x; 2.1166x over previous
//
#include <hip/hip_runtime.h>

// Problem constants
#define NPIX 8192      // B*H*W
#define EDIM 256
#define KCB  8192
#define OUT_ZQ   0
#define OUT_DIFF 2097152
#define OUT_IND  2097153

// ws layout (bytes) — total 331,776 <= proven 565,248
#define WS_A     0         // 8192 f32  np-pairwise ||z_e||^2
#define WS_N     32768     // 8192 f32  np-pairwise ||e||^2
#define WS_PAIRS 65536     // 8192*4 float2 = 256 KB
#define WS_PART  327680    // 1024 f32

// ---------------------------------------------------------------- z_e: bit-exact np.einsum replica
__global__ __launch_bounds__(256) void k_ze_np(const float* __restrict__ z,
                                               const float* __restrict__ pw,
                                               const float* __restrict__ pb,
                                               float* __restrict__ ze) {
    __shared__ float lz[32][16];
    __shared__ float lw[256][33];
    const int t   = threadIdx.x;
    const int b   = blockIdx.x >> 6;
    const int hw0 = (blockIdx.x & 63) * 16;

    float acc[16];
#pragma unroll
    for (int p = 0; p < 16; ++p) acc[p] = 0.0f;

    for (int cc = 0; cc < 256; cc += 32) {
        float4 wv[8];
        const float4* wsrc = reinterpret_cast<const float4*>(pw + (size_t)t * 256 + cc);
#pragma unroll
        for (int i = 0; i < 8; ++i) wv[i] = wsrc[i];
        float zv[2];
#pragma unroll
        for (int i = 0; i < 2; ++i) {
            const int f = t + i * 256;           // 0..511
            zv[i] = z[(size_t)(b * 256 + cc + (f >> 4)) * 1024 + hw0 + (f & 15)];
        }
        __syncthreads();   // previous chunk's reads complete
#pragma unroll
        for (int i = 0; i < 8; ++i) {
            lw[t][i * 4 + 0] = wv[i].x;
            lw[t][i * 4 + 1] = wv[i].y;
            lw[t][i * 4 + 2] = wv[i].z;
            lw[t][i * 4 + 3] = wv[i].w;
        }
#pragma unroll
        for (int i = 0; i < 2; ++i) {
            const int f = t + i * 256;
            lz[f >> 4][f & 15] = zv[i];
        }
        __syncthreads();
#pragma unroll 8
        for (int cl = 0; cl < 32; ++cl) {
            const float wl = lw[t][cl];
#pragma unroll
            for (int p = 0; p < 16; ++p)
                acc[p] = __fadd_rn(acc[p], __fmul_rn(lz[cl][p], wl));
        }
    }
    const float bb = pb[t];
#pragma unroll
    for (int p = 0; p < 16; ++p)
        ze[(size_t)(b * 1024 + hw0 + p) * 256 + t] = __fadd_rn(acc[p], bb);
}

// ---------------------------------------------------------------- np.sum(x*x, axis=1) pairwise replica (n=256)
__global__ __launch_bounds__(256) void k_rowstats(const float* __restrict__ ze,
                                                  const float* __restrict__ embed,
                                                  float* __restrict__ A,
                                                  float* __restrict__ Nf) {
    const int gid = blockIdx.x * 256 + threadIdx.x;     // 0..16383
    const float* row = (gid < 8192) ? (ze + (size_t)gid * 256)
                                    : (embed + (size_t)(gid - 8192) * 256);
    float blk[2];
#pragma unroll
    for (int half = 0; half < 2; ++half) {
        const float4* r4 = reinterpret_cast<const float4*>(row + half * 128);
        float r[8];
#pragma unroll
        for (int i = 0; i < 16; ++i) {
            const float4 a = r4[i * 2], b = r4[i * 2 + 1];
            const float s[8] = {__fmul_rn(a.x, a.x), __fmul_rn(a.y, a.y),
                                __fmul_rn(a.z, a.z), __fmul_rn(a.w, a.w),
                                __fmul_rn(b.x, b.x), __fmul_rn(b.y, b.y),
                                __fmul_rn(b.z, b.z), __fmul_rn(b.w, b.w)};
            if (i == 0) {
#pragma unroll
                for (int j = 0; j < 8; ++j) r[j] = s[j];
            } else {
#pragma unroll
                for (int j = 0; j < 8; ++j) r[j] = __fadd_rn(r[j], s[j]);
            }
        }
        blk[half] = __fadd_rn(__fadd_rn(__fadd_rn(r[0], r[1]), __fadd_rn(r[2], r[3])),
                              __fadd_rn(__fadd_rn(r[4], r[5]), __fadd_rn(r[6], r[7])));
    }
    const float res = __fadd_rn(blk[0], blk[1]);
    if (gid < 8192) A[gid] = res;
    else            Nf[gid - 8192] = res;
}

// ---------------------------------------------------------------- dist replica + argmin, LDS-only inner loop
// grid 1024 = 256 px-tiles(32 px) x 4 k-splits(2048 k). 256 thr = 4 tp x 64 tk.
// thread tile: 8 px (px = tp+4i) x 4 k (k = tk*4+j). kc chunks 256 k, cc passes 32 c.
// lz2 holds 2*z_e (exact prescale); chain fmaf(zq.y, eb, fmaf(zq.x, ea, acc)) = bit-identical to round-5.
__global__ __launch_bounds__(256, 4) void k_dist_np(const float* __restrict__ ze,
                                                    const float* __restrict__ embed,
                                                    const float* __restrict__ A,
                                                    const float* __restrict__ Nf,
                                                    float2* __restrict__ pairs) {
    __shared__ __align__(16) char smem[36864];
    float  (*le)[256] = reinterpret_cast<float (*)[256]>(smem);          // [c32][k256] 32KB
    float2 (*lz2)[32] = reinterpret_cast<float2 (*)[32]>(smem + 32768);  // [ch16][px32] 4KB
    float*  red       = reinterpret_cast<float*>(smem);                  // overlay [32px][64tk][2]

    const int t    = threadIdx.x;
    const int ks   = blockIdx.x & 3;
    const int pt   = blockIdx.x >> 2;
    const int pix0 = pt * 32;
    const int k0   = ks * 2048;
    const int tp   = t & 3, tk = t >> 2;
    const int spx  = t & 31, sch = t >> 5;     // lz2 staging coords

    float best[8];
    int   bidx[8];
#pragma unroll
    for (int i = 0; i < 8; ++i) { best[i] = 3.402823466e+38f; bidx[i] = 0x7fffffff; }

    float Ai[8];
#pragma unroll
    for (int i = 0; i < 8; ++i) Ai[i] = A[pix0 + tp + 4 * i];

    for (int kc = 0; kc < 2048; kc += 256) {
        float acc[8][4];
#pragma unroll
        for (int i = 0; i < 8; ++i)
#pragma unroll
            for (int j = 0; j < 4; ++j) acc[i][j] = 0.0f;

        const float* erow = embed + (size_t)(k0 + kc + t) * 256;

        for (int cc = 0; cc < 256; cc += 32) {
            // prefetch embed row chunk + z_e chunk into regs
            float4 st[8];
            const float4* src = reinterpret_cast<const float4*>(erow + cc);
#pragma unroll
            for (int m = 0; m < 8; ++m) st[m] = src[m];
            float2 zv[2];
#pragma unroll
            for (int p = 0; p < 2; ++p) {
                const int ch = sch + 8 * p;
                zv[p] = *reinterpret_cast<const float2*>(
                    ze + (size_t)(pix0 + spx) * 256 + cc + 2 * ch);
            }
            __syncthreads();   // prior inner-loop reads of le/lz2 complete
#pragma unroll
            for (int m = 0; m < 8; ++m) {
                le[m * 4 + 0][t] = st[m].x;
                le[m * 4 + 1][t] = st[m].y;
                le[m * 4 + 2][t] = st[m].z;
                le[m * 4 + 3][t] = st[m].w;
            }
#pragma unroll
            for (int p = 0; p < 2; ++p) {
                const int ch = sch + 8 * p;
                lz2[ch][spx] = make_float2(__fmul_rn(2.0f, zv[p].x),
                                           __fmul_rn(2.0f, zv[p].y));   // exact prescale
            }
            __syncthreads();
#pragma unroll
            for (int ch = 0; ch < 16; ++ch) {
                float2 zq[8];
#pragma unroll
                for (int i = 0; i < 8; ++i) zq[i] = lz2[ch][tp + 4 * i];
                const float4 ea = *reinterpret_cast<const float4*>(&le[2 * ch][tk * 4]);
                const float4 eb = *reinterpret_cast<const float4*>(&le[2 * ch + 1][tk * 4]);
#pragma unroll
                for (int i = 0; i < 8; ++i) {
                    acc[i][0] = fmaf(zq[i].y, eb.x, fmaf(zq[i].x, ea.x, acc[i][0]));
                    acc[i][1] = fmaf(zq[i].y, eb.y, fmaf(zq[i].x, ea.y, acc[i][1]));
                    acc[i][2] = fmaf(zq[i].y, eb.z, fmaf(zq[i].x, ea.z, acc[i][2]));
                    acc[i][3] = fmaf(zq[i].y, eb.w, fmaf(zq[i].x, ea.w, acc[i][3]));
                }
            }
        }
        // scores; thread-local k ascending -> strict < keeps first occurrence
        const float4 nk4 = *reinterpret_cast<const float4*>(&Nf[k0 + kc + tk * 4]);
        const float nk[4] = {nk4.x, nk4.y, nk4.z, nk4.w};
#pragma unroll
        for (int j = 0; j < 4; ++j) {
            const int k = k0 + kc + tk * 4 + j;
#pragma unroll
            for (int i = 0; i < 8; ++i) {
                const float v = __fadd_rn(__fsub_rn(Ai[i], acc[i][j]), nk[j]);
                if (v < best[i]) { best[i] = v; bidx[i] = k; }
            }
        }
    }
    __syncthreads();   // all le/lz2 reads done; overlay reduction buffer
#pragma unroll
    for (int i = 0; i < 8; ++i) {
        const int px = tp + 4 * i;
        red[(px * 64 + tk) * 2 + 0] = best[i];
        red[(px * 64 + tk) * 2 + 1] = __int_as_float(bidx[i]);
    }
    __syncthreads();
    if (t < 32) {
        float bv = 3.402823466e+38f;
        int   bk = 0x7fffffff;
#pragma unroll 4
        for (int q = 0; q < 64; ++q) {
            const float v  = red[(t * 64 + q) * 2 + 0];
            const int   ki = __float_as_int(red[(t * 64 + q) * 2 + 1]);
            if (v < bv || (v == bv && ki < bk)) { bv = v; bk = ki; }
        }
        pairs[(size_t)(pix0 + t) * 4 + ks] = make_float2(bv, (float)bk);
    }
}

// ---------------------------------------------------------------- combine 4 k-splits (lexicographic)
__global__ __launch_bounds__(256) void k_combine(const float2* __restrict__ pairs,
                                                 float* __restrict__ out_ind) {
    const int n = blockIdx.x * 256 + threadIdx.x;
    float bv = 3.402823466e+38f;
    float bk = 1.0e9f;
#pragma unroll
    for (int s = 0; s < 4; ++s) {
        const float2 p = pairs[(size_t)n * 4 + s];
        if (p.x < bv || (p.x == bv && p.y < bk)) { bv = p.x; bk = p.y; }
    }
    out_ind[n] = bk;
}

// ---------------------------------------------------------------- gather z_q (overwrite z_e) + partial MSE (f64)
__global__ __launch_bounds__(256) void k_gather(const float* __restrict__ embed,
                                                float* __restrict__ out,
                                                const float* __restrict__ out_ind,
                                                float* __restrict__ part) {
    __shared__ double wsum[4];
    const int t = threadIdx.x;
    const int g = t >> 5, l = t & 31;
    const int n = blockIdx.x * 8 + g;
    const int idx = (int)(out_ind[n] + 0.5f);
    const float4* ev4 = reinterpret_cast<const float4*>(embed + (size_t)idx * EDIM);
    float4* zp = reinterpret_cast<float4*>(out + (size_t)n * EDIM);
    double s = 0.0;
#pragma unroll
    for (int r = 0; r < 2; ++r) {
        const float4 ev = ev4[l + r * 32];
        const float4 zv = zp[l + r * 32];
        const double dx = (double)ev.x - zv.x, dy = (double)ev.y - zv.y;
        const double dz = (double)ev.z - zv.z, dw = (double)ev.w - zv.w;
        s += dx * dx + dy * dy + dz * dz + dw * dw;
        zp[l + r * 32] = ev;             // z_q_st == z_q numerically
    }
    for (int off = 32; off; off >>= 1) s += __shfl_down(s, off, 64);
    const int wid = t >> 6, lane = t & 63;
    if (lane == 0) wsum[wid] = s;
    __syncthreads();
    if (t == 0) part[blockIdx.x] = (float)(wsum[0] + wsum[1] + wsum[2] + wsum[3]);
}

// ---------------------------------------------------------------- final diff reduction (f64)
__global__ __launch_bounds__(256) void k_final(const float* __restrict__ part,
                                               float* __restrict__ out_diff) {
    __shared__ double wsum[4];
    double s = 0.0;
#pragma unroll
    for (int i = 0; i < 4; ++i) s += (double)part[threadIdx.x + i * 256];
    for (int off = 32; off; off >>= 1) s += __shfl_down(s, off, 64);
    const int wid = threadIdx.x >> 6, lane = threadIdx.x & 63;
    if (lane == 0) wsum[wid] = s;
    __syncthreads();
    if (threadIdx.x == 0)
        out_diff[0] = (float)(2.0 * (wsum[0] + wsum[1] + wsum[2] + wsum[3]) / 2097152.0);
}

extern "C" void kernel_launch(void* const* d_in, const int* in_sizes, int n_in,
                              void* d_out, int out_size, void* d_ws, size_t ws_size,
                              hipStream_t stream) {
    const float* z     = (const float*)d_in[0];
    const float* pw    = (const float*)d_in[1];
    const float* pb    = (const float*)d_in[2];
    const float* embed = (const float*)d_in[3];
    float* out = (float*)d_out;
    char*  ws  = (char*)d_ws;

    float*  A     = (float*)(ws + WS_A);
    float*  Nf    = (float*)(ws + WS_N);
    float2* pairs = (float2*)(ws + WS_PAIRS);
    float*  part  = (float*)(ws + WS_PART);

    float* ze       = out + OUT_ZQ;      // z_e lives in z_q slot, overwritten by gather
    float* out_diff = out + OUT_DIFF;
    float* out_ind  = out + OUT_IND;

    k_ze_np   <<<512,  256, 0, stream>>>(z, pw, pb, ze);
    k_rowstats<<<64,   256, 0, stream>>>(ze, embed, A, Nf);
    k_dist_np <<<1024, 256, 0, stream>>>(ze, embed, A, Nf, pairs);
    k_combine <<<32,   256, 0, stream>>>(pairs, out_ind);
    k_gather  <<<1024, 256, 0, stream>>>(embed, out + OUT_ZQ, out_ind, part);
    k_final   <<<1,    256, 0, stream>>>(part, out_diff);
}

// Round 7
// 530.510 us; speedup vs baseline: 2.2455x; 1.0609x over previous
//
#include <hip/hip_runtime.h>

// Problem constants
#define NPIX 8192      // B*H*W
#define EDIM 256
#define KCB  8192
#define OUT_ZQ   0
#define OUT_DIFF 2097152
#define OUT_IND  2097153

// ws layout (bytes) — total 462,848 <= proven 565,248
#define WS_A     0         // 8192 f32
#define WS_N     32768     // 8192 f32
#define WS_PVAL  65536     // 8192*8 f32 = 256 KB
#define WS_PIDX  327680    // 8192*8 u16 = 128 KB
#define WS_PART  458752    // 1024 f32

// ---------------------------------------------------------------- z_e: bit-exact np.einsum replica
__global__ __launch_bounds__(256) void k_ze_np(const float* __restrict__ z,
                                               const float* __restrict__ pw,
                                               const float* __restrict__ pb,
                                               float* __restrict__ ze) {
    __shared__ float lz[32][16];
    __shared__ float lw[256][33];
    const int t   = threadIdx.x;
    const int b   = blockIdx.x >> 6;
    const int hw0 = (blockIdx.x & 63) * 16;

    float acc[16];
#pragma unroll
    for (int p = 0; p < 16; ++p) acc[p] = 0.0f;

    for (int cc = 0; cc < 256; cc += 32) {
        float4 wv[8];
        const float4* wsrc = reinterpret_cast<const float4*>(pw + (size_t)t * 256 + cc);
#pragma unroll
        for (int i = 0; i < 8; ++i) wv[i] = wsrc[i];
        float zv[2];
#pragma unroll
        for (int i = 0; i < 2; ++i) {
            const int f = t + i * 256;           // 0..511
            zv[i] = z[(size_t)(b * 256 + cc + (f >> 4)) * 1024 + hw0 + (f & 15)];
        }
        __syncthreads();   // previous chunk's reads complete
#pragma unroll
        for (int i = 0; i < 8; ++i) {
            lw[t][i * 4 + 0] = wv[i].x;
            lw[t][i * 4 + 1] = wv[i].y;
            lw[t][i * 4 + 2] = wv[i].z;
            lw[t][i * 4 + 3] = wv[i].w;
        }
#pragma unroll
        for (int i = 0; i < 2; ++i) {
            const int f = t + i * 256;
            lz[f >> 4][f & 15] = zv[i];
        }
        __syncthreads();
#pragma unroll 8
        for (int cl = 0; cl < 32; ++cl) {
            const float wl = lw[t][cl];
#pragma unroll
            for (int p = 0; p < 16; ++p)
                acc[p] = __fadd_rn(acc[p], __fmul_rn(lz[cl][p], wl));
        }
    }
    const float bb = pb[t];
#pragma unroll
    for (int p = 0; p < 16; ++p)
        ze[(size_t)(b * 1024 + hw0 + p) * 256 + t] = __fadd_rn(acc[p], bb);
}

// ---------------------------------------------------------------- np.sum(x*x, axis=1) pairwise replica (n=256)
__global__ __launch_bounds__(256) void k_rowstats(const float* __restrict__ ze,
                                                  const float* __restrict__ embed,
                                                  float* __restrict__ A,
                                                  float* __restrict__ Nf) {
    const int gid = blockIdx.x * 256 + threadIdx.x;     // 0..16383
    const float* row = (gid < 8192) ? (ze + (size_t)gid * 256)
                                    : (embed + (size_t)(gid - 8192) * 256);
    float blk[2];
#pragma unroll
    for (int half = 0; half < 2; ++half) {
        const float4* r4 = reinterpret_cast<const float4*>(row + half * 128);
        float r[8];
#pragma unroll
        for (int i = 0; i < 16; ++i) {
            const float4 a = r4[i * 2], b = r4[i * 2 + 1];
            const float s[8] = {__fmul_rn(a.x, a.x), __fmul_rn(a.y, a.y),
                                __fmul_rn(a.z, a.z), __fmul_rn(a.w, a.w),
                                __fmul_rn(b.x, b.x), __fmul_rn(b.y, b.y),
                                __fmul_rn(b.z, b.z), __fmul_rn(b.w, b.w)};
            if (i == 0) {
#pragma unroll
                for (int j = 0; j < 8; ++j) r[j] = s[j];
            } else {
#pragma unroll
                for (int j = 0; j < 8; ++j) r[j] = __fadd_rn(r[j], s[j]);
            }
        }
        blk[half] = __fadd_rn(__fadd_rn(__fadd_rn(r[0], r[1]), __fadd_rn(r[2], r[3])),
                              __fadd_rn(__fadd_rn(r[4], r[5]), __fadd_rn(r[6], r[7])));
    }
    const float res = __fadd_rn(blk[0], blk[1]);
    if (gid < 8192) A[gid] = res;
    else            Nf[gid - 8192] = res;
}

// ---------------------------------------------------------------- dist replica + argmin, b128-only LDS inner loop
// grid 1024 = 128 px-tiles(64 px) x 8 k-splits(1024 k). 256 thr = 8 tp x 32 tk.
// thread tile: 8 px (px = tp*8+i, consecutive) x 8 k (k = tk*8+j). kc chunks 256 k, cc passes 32 c.
// lzp[pair][ch ^ (pair>>2)] = float4(2z[p0][c0],2z[p0][c1],2z[p1][c0],2z[p1][c1])  (swizzle -> conflict-free reads)
// chain per (px,k): c ascending, fmaf(c1, fmaf(c0, acc)) — bit-identical to round-5/6.
__global__ __launch_bounds__(256, 4) void k_dist_np(const float* __restrict__ ze,
                                                    const float* __restrict__ embed,
                                                    const float* __restrict__ A,
                                                    const float* __restrict__ Nf,
                                                    float* __restrict__ pval,
                                                    unsigned short* __restrict__ pidx) {
    __shared__ __align__(16) char smem[40960];
    float  (*le)[256] = reinterpret_cast<float (*)[256]>(smem);          // [c32][k256] 32 KB
    float4 (*lzp)[16] = reinterpret_cast<float4 (*)[16]>(smem + 32768);  // [pair32][ch16] 8 KB
    float*  red       = reinterpret_cast<float*>(smem);                  // overlay [64px][32tk][2] 16 KB

    const int t    = threadIdx.x;
    const int ks   = blockIdx.x & 7;
    const int pt   = blockIdx.x >> 3;
    const int pix0 = pt * 64;
    const int k0   = ks * 1024;
    const int tp   = t & 7, tk = t >> 3;       // compute coords
    const int spx  = t & 63, sg = t >> 6;      // staging coords

    float best[8];
    int   bidx[8];
#pragma unroll
    for (int i = 0; i < 8; ++i) { best[i] = 3.402823466e+38f; bidx[i] = 0x7fffffff; }

    float Ai[8];
#pragma unroll
    for (int i = 0; i < 8; ++i) Ai[i] = A[pix0 + tp * 8 + i];

    for (int kc = 0; kc < 1024; kc += 256) {
        float acc[8][8];
#pragma unroll
        for (int i = 0; i < 8; ++i)
#pragma unroll
            for (int j = 0; j < 8; ++j) acc[i][j] = 0.0f;

        const float* erow = embed + (size_t)(k0 + kc + t) * 256;

        for (int cc = 0; cc < 256; cc += 32) {
            // prefetch embed row chunk (row k0+kc+t, 32 c) and z chunk (px spx, 8 c) into regs
            float4 st[8];
            const float4* src = reinterpret_cast<const float4*>(erow + cc);
#pragma unroll
            for (int m = 0; m < 8; ++m) st[m] = src[m];
            const float4* zsrc = reinterpret_cast<const float4*>(
                ze + (size_t)(pix0 + spx) * 256 + cc + 8 * sg);
            const float4 zf0 = zsrc[0], zf1 = zsrc[1];
            __syncthreads();   // prior inner-loop reads of le/lzp complete
#pragma unroll
            for (int m = 0; m < 8; ++m) {
                le[m * 4 + 0][t] = st[m].x;
                le[m * 4 + 1][t] = st[m].y;
                le[m * 4 + 2][t] = st[m].z;
                le[m * 4 + 3][t] = st[m].w;
            }
            {
                const int pr = spx >> 1, par = spx & 1;
                const int sw = (pr >> 2) & 7;
                const float zc[8] = {zf0.x, zf0.y, zf0.z, zf0.w, zf1.x, zf1.y, zf1.z, zf1.w};
#pragma unroll
                for (int p = 0; p < 4; ++p) {
                    const int ch = sg * 4 + p;
                    float2* dst = reinterpret_cast<float2*>(&lzp[pr][ch ^ sw]) + par;
                    *dst = make_float2(__fmul_rn(2.0f, zc[2 * p]),
                                       __fmul_rn(2.0f, zc[2 * p + 1]));   // exact prescale
                }
            }
            __syncthreads();
#pragma unroll 4
            for (int ch = 0; ch < 16; ++ch) {
                const float4 ea  = *reinterpret_cast<const float4*>(&le[2 * ch][tk * 8]);
                const float4 ea2 = *reinterpret_cast<const float4*>(&le[2 * ch][tk * 8 + 4]);
                const float4 eb  = *reinterpret_cast<const float4*>(&le[2 * ch + 1][tk * 8]);
                const float4 eb2 = *reinterpret_cast<const float4*>(&le[2 * ch + 1][tk * 8 + 4]);
#define FMA8(i, zx, zy)                                              \
    acc[i][0] = fmaf(zy, eb.x,  fmaf(zx, ea.x,  acc[i][0]));         \
    acc[i][1] = fmaf(zy, eb.y,  fmaf(zx, ea.y,  acc[i][1]));         \
    acc[i][2] = fmaf(zy, eb.z,  fmaf(zx, ea.z,  acc[i][2]));         \
    acc[i][3] = fmaf(zy, eb.w,  fmaf(zx, ea.w,  acc[i][3]));         \
    acc[i][4] = fmaf(zy, eb2.x, fmaf(zx, ea2.x, acc[i][4]));         \
    acc[i][5] = fmaf(zy, eb2.y, fmaf(zx, ea2.y, acc[i][5]));         \
    acc[i][6] = fmaf(zy, eb2.z, fmaf(zx, ea2.z, acc[i][6]));         \
    acc[i][7] = fmaf(zy, eb2.w, fmaf(zx, ea2.w, acc[i][7]));
#pragma unroll
                for (int q = 0; q < 4; ++q) {
                    const int pr = tp * 4 + q;                 // (pr>>2)&7 == tp
                    const float4 zp = lzp[pr][ch ^ tp];
                    FMA8(2 * q,     zp.x, zp.y)
                    FMA8(2 * q + 1, zp.z, zp.w)
                }
#undef FMA8
            }
        }
        // scores; thread-local k ascending -> strict < keeps first occurrence
        const float4 nka = *reinterpret_cast<const float4*>(&Nf[k0 + kc + tk * 8]);
        const float4 nkb = *reinterpret_cast<const float4*>(&Nf[k0 + kc + tk * 8 + 4]);
        const float nk[8] = {nka.x, nka.y, nka.z, nka.w, nkb.x, nkb.y, nkb.z, nkb.w};
#pragma unroll
        for (int j = 0; j < 8; ++j) {
            const int k = k0 + kc + tk * 8 + j;
#pragma unroll
            for (int i = 0; i < 8; ++i) {
                const float v = __fadd_rn(__fsub_rn(Ai[i], acc[i][j]), nk[j]);
                if (v < best[i]) { best[i] = v; bidx[i] = k; }
            }
        }
    }
    __syncthreads();   // all le/lzp reads done; overlay reduction buffer
#pragma unroll
    for (int i = 0; i < 8; ++i) {
        const int px = tp * 8 + i;
        red[(px * 32 + tk) * 2 + 0] = best[i];
        red[(px * 32 + tk) * 2 + 1] = __int_as_float(bidx[i]);
    }
    __syncthreads();
    if (t < 64) {
        float bv = 3.402823466e+38f;
        int   bk = 0x7fffffff;
#pragma unroll 4
        for (int q = 0; q < 32; ++q) {   // tk ascending == k ascending
            const float v  = red[(t * 32 + q) * 2 + 0];
            const int   ki = __float_as_int(red[(t * 32 + q) * 2 + 1]);
            if (v < bv || (v == bv && ki < bk)) { bv = v; bk = ki; }
        }
        pval[(size_t)(pix0 + t) * 8 + ks] = bv;
        pidx[(size_t)(pix0 + t) * 8 + ks] = (unsigned short)bk;
    }
}

// ---------------------------------------------------------------- combine 8 k-splits (lexicographic)
__global__ __launch_bounds__(256) void k_combine(const float* __restrict__ pval,
                                                 const unsigned short* __restrict__ pidx,
                                                 float* __restrict__ out_ind) {
    const int n = blockIdx.x * 256 + threadIdx.x;
    float bv = 3.402823466e+38f;
    int   bk = 0x7fffffff;
#pragma unroll
    for (int s = 0; s < 8; ++s) {        // ks ascending == k ascending
        const float v  = pval[(size_t)n * 8 + s];
        const int   ki = pidx[(size_t)n * 8 + s];
        if (v < bv || (v == bv && ki < bk)) { bv = v; bk = ki; }
    }
    out_ind[n] = (float)bk;
}

// ---------------------------------------------------------------- gather z_q (overwrite z_e) + partial MSE (f64)
__global__ __launch_bounds__(256) void k_gather(const float* __restrict__ embed,
                                                float* __restrict__ out,
                                                const float* __restrict__ out_ind,
                                                float* __restrict__ part) {
    __shared__ double wsum[4];
    const int t = threadIdx.x;
    const int g = t >> 5, l = t & 31;
    const int n = blockIdx.x * 8 + g;
    const int idx = (int)(out_ind[n] + 0.5f);
    const float4* ev4 = reinterpret_cast<const float4*>(embed + (size_t)idx * EDIM);
    float4* zp = reinterpret_cast<float4*>(out + (size_t)n * EDIM);
    double s = 0.0;
#pragma unroll
    for (int r = 0; r < 2; ++r) {
        const float4 ev = ev4[l + r * 32];
        const float4 zv = zp[l + r * 32];
        const double dx = (double)ev.x - zv.x, dy = (double)ev.y - zv.y;
        const double dz = (double)ev.z - zv.z, dw = (double)ev.w - zv.w;
        s += dx * dx + dy * dy + dz * dz + dw * dw;
        zp[l + r * 32] = ev;             // z_q_st == z_q numerically
    }
    for (int off = 32; off; off >>= 1) s += __shfl_down(s, off, 64);
    const int wid = t >> 6, lane = t & 63;
    if (lane == 0) wsum[wid] = s;
    __syncthreads();
    if (t == 0) part[blockIdx.x] = (float)(wsum[0] + wsum[1] + wsum[2] + wsum[3]);
}

// ---------------------------------------------------------------- final diff reduction (f64)
__global__ __launch_bounds__(256) void k_final(const float* __restrict__ part,
                                               float* __restrict__ out_diff) {
    __shared__ double wsum[4];
    double s = 0.0;
#pragma unroll
    for (int i = 0; i < 4; ++i) s += (double)part[threadIdx.x + i * 256];
    for (int off = 32; off; off >>= 1) s += __shfl_down(s, off, 64);
    const int wid = threadIdx.x >> 6, lane = threadIdx.x & 63;
    if (lane == 0) wsum[wid] = s;
    __syncthreads();
    if (threadIdx.x == 0)
        out_diff[0] = (float)(2.0 * (wsum[0] + wsum[1] + wsum[2] + wsum[3]) / 2097152.0);
}

extern "C" void kernel_launch(void* const* d_in, const int* in_sizes, int n_in,
                              void* d_out, int out_size, void* d_ws, size_t ws_size,
                              hipStream_t stream) {
    const float* z     = (const float*)d_in[0];
    const float* pw    = (const float*)d_in[1];
    const float* pb    = (const float*)d_in[2];
    const float* embed = (const float*)d_in[3];
    float* out = (float*)d_out;
    char*  ws  = (char*)d_ws;

    float*          A    = (float*)(ws + WS_A);
    float*          Nf   = (float*)(ws + WS_N);
    float*          pval = (float*)(ws + WS_PVAL);
    unsigned short* pidx = (unsigned short*)(ws + WS_PIDX);
    float*          part = (float*)(ws + WS_PART);

    float* ze       = out + OUT_ZQ;      // z_e lives in z_q slot, overwritten by gather
    float* out_diff = out + OUT_DIFF;
    float* out_ind  = out + OUT_IND;

    k_ze_np   <<<512,  256, 0, stream>>>(z, pw, pb, ze);
    k_rowstats<<<64,   256, 0, stream>>>(ze, embed, A, Nf);
    k_dist_np <<<1024, 256, 0, stream>>>(ze, embed, A, Nf, pval, pidx);
    k_combine <<<32,   256, 0, stream>>>(pval, pidx, out_ind);
    k_gather  <<<1024, 256, 0, stream>>>(embed, out + OUT_ZQ, out_ind, part);
    k_final   <<<1,    256, 0, stream>>>(part, out_diff);
}